// Round 5
// baseline (20466.473 us; speedup 1.0000x reference)
//
#include <hip/hip_runtime.h>

#define NN 500
#define BB 8
#define FIN 8
#define TT 12
#define HH 16
#define EE 8000
#define HG 4000          // N*HID
#define IG 8000          // N*H3
#define G3 12000         // 3*HG
#define MM 96            // T*B
#define KP 4096          // padded W_hh row length (halves)

typedef __attribute__((ext_vector_type(8))) _Float16 half8;
typedef __attribute__((ext_vector_type(4))) _Float16 half4v;
typedef __attribute__((ext_vector_type(4))) float f32x4;

// ---------------------------------------------------------------- graph prep
__global__ __launch_bounds__(512) void k_prep(const int* __restrict__ src,
                                              const int* __restrict__ dst,
                                              float* __restrict__ n_out,
                                              float* __restrict__ n_in,
                                              int* __restrict__ row_ptr,
                                              int* __restrict__ edge_src) {
  __shared__ int s_dout[NN];
  __shared__ int s_din[NN];
  __shared__ int s_off[NN + 1];
  int tid = threadIdx.x;
  for (int i = tid; i < NN; i += 512) { s_dout[i] = 0; s_din[i] = 0; }
  __syncthreads();
  for (int e = tid; e < EE; e += 512) {
    atomicAdd(&s_dout[src[e]], 1);
    atomicAdd(&s_din[dst[e]], 1);
  }
  __syncthreads();
  if (tid == 0) {
    int acc = 0;
    for (int n = 0; n < NN; ++n) { s_off[n] = acc; acc += s_din[n]; }
    s_off[NN] = acc;
  }
  __syncthreads();
  for (int i = tid; i < NN; i += 512) {
    int dv = s_dout[i]; if (dv < 1) dv = 1;
    int iv = s_din[i];  if (iv < 1) iv = 1;
    n_out[i] = rsqrtf((float)dv);
    n_in[i]  = rsqrtf((float)iv);
    row_ptr[i] = s_off[i];
  }
  if (tid == 0) row_ptr[NN] = s_off[NN];
  __syncthreads();
  for (int e = tid; e < EE; e += 512) {
    int d = dst[e];
    int pos = atomicAdd(&s_off[d], 1);
    edge_src[pos] = src[e];
  }
}

// ------------------------------------------------- transpose inputs to [t][n][b][f]
__global__ __launch_bounds__(256) void k_transpose(const float* __restrict__ in,
                                                   float* __restrict__ out) {
  int idx = blockIdx.x * 256 + threadIdx.x;   // over T*N*B*FIN
  if (idx >= TT * NN * BB * FIN) return;
  int f = idx % FIN;
  int b = (idx / FIN) % BB;
  int n = (idx / (FIN * BB)) % NN;
  int t = idx / (FIN * BB * NN);
  out[idx] = in[((n * BB + b) * FIN + f) * TT + t];
}

// ---------------------------------------------------------------- GCN layer
template <int FI, int FO, bool RELU, typename OT, bool OUT_SEQ>
__global__ __launch_bounds__(128) void k_gcn(const float* __restrict__ x,
                                             const float* __restrict__ W,
                                             const float* __restrict__ bias,
                                             const float* __restrict__ n_out,
                                             const float* __restrict__ n_in,
                                             const int* __restrict__ row_ptr,
                                             const int* __restrict__ edge_src,
                                             OT* __restrict__ y) {
  int bid = blockIdx.x;             // t*NN + n
  int t = bid / NN, n = bid % NN;
  __shared__ float sW[FI * FO];
  __shared__ float sB[FO];
  __shared__ float sAgg[BB * FI];
  int tid = threadIdx.x;
  for (int i = tid; i < FI * FO; i += 128) sW[i] = W[i];
  if (tid < FO) sB[tid] = bias[tid];
  int r0 = row_ptr[n], r1 = row_ptr[n + 1];
  if (tid < BB * FI) {
    int b = tid / FI, fi = tid % FI;
    float acc = 0.f;
    for (int p = r0; p < r1; ++p) {
      int s = edge_src[p];
      acc += x[((t * NN + s) * BB + b) * FI + fi] * n_out[s];
    }
    sAgg[tid] = acc * n_in[n];
  }
  __syncthreads();
  if (tid < BB * FO) {
    int b = tid / FO, fo = tid % FO;
    float v = sB[fo];
#pragma unroll
    for (int fi = 0; fi < FI; ++fi) v += sAgg[b * FI + fi] * sW[fi * FO + fo];
    if (RELU) v = fmaxf(v, 0.f);
    int oidx = OUT_SEQ ? (((t * BB + b) * NN + n) * FO + fo)
                       : (((t * NN + n) * BB + b) * FO + fo);
    y[oidx] = (OT)v;
  }
}

// ------------------------ Whh fp32 [12000][4000] -> fp16 [12000][4096] (pad 0)
__global__ __launch_bounds__(256) void k_cvt_whh(const float* __restrict__ w,
                                                 _Float16* __restrict__ wh) {
  int u = blockIdx.x * 256 + threadIdx.x;     // half8 unit id; grid exact 24000
  int row = u >> 9, c = u & 511;              // 512 units per padded row
  int col = c * 8;
  half8 h = {};
  if (col < HG) {                             // 4000 % 8 == 0: no straddle
    const float* p = w + (size_t)row * HG + col;
    float4 a = *(const float4*)p;
    float4 b = *(const float4*)(p + 4);
    h[0] = (_Float16)a.x; h[1] = (_Float16)a.y; h[2] = (_Float16)a.z; h[3] = (_Float16)a.w;
    h[4] = (_Float16)b.x; h[5] = (_Float16)b.y; h[6] = (_Float16)b.z; h[7] = (_Float16)b.w;
  }
  ((half8*)wh)[u] = h;
}

// ------------------------------------------------------------ gi = X @ Wih^T
// fp16 MFMA single pass.  Xh: [96][8000] fp16, Wih: [12000][8000] fp32 (cvt in-kernel).
// gip: [2][96][12000] K-split partials.  grid (375, 2), block 256 (4 waves).
__global__ __launch_bounds__(256, 3) void k_gemm_gi_mfma(const _Float16* __restrict__ Xh,
                                                         const float* __restrict__ Wih,
                                                         float* __restrict__ gip) {
  __shared__ _Float16 sXh[96 * 40];   // rows padded to 40 halves (80B stride)
  __shared__ _Float16 sWh[32 * 40];
  int tid = threadIdx.x;
  int wave = tid >> 6, lane = tid & 63;
  int jb = blockIdx.x * 32;
  int kbase = blockIdx.y * 4000;       // K_s = 4000, 125 chunks of 32

  int xrow[3], xc4[3];
  const ushort4* px[3];
#pragma unroll
  for (int i = 0; i < 3; ++i) {
    int idx = i * 256 + tid;           // 768 units = 96 rows x 8 half4
    xrow[i] = idx >> 3; xc4[i] = idx & 7;
    px[i] = (const ushort4*)(Xh + (size_t)xrow[i] * IG + kbase + xc4[i] * 4);
  }
  int wrow = tid >> 3, wc4 = tid & 7;  // 256 f4 = 32 rows x 8 f4
  const float4* pw = (const float4*)(Wih + (size_t)(jb + wrow) * IG + kbase + wc4 * 4);

  int jt = wave & 1;                    // j-tile within block
  int mh = wave >> 1;                   // m-half (48 rows)
  f32x4 acc[3] = {{0.f,0.f,0.f,0.f},{0.f,0.f,0.f,0.f},{0.f,0.f,0.f,0.f}};

  ushort4 xr[3]; float4 wr;
#pragma unroll
  for (int i = 0; i < 3; ++i) xr[i] = px[i][0];
  wr = pw[0];

  int l15 = lane & 15;
  int colh = (lane >> 4) * 8;

  for (int c = 0; c < 125; ++c) {
    __syncthreads();
#pragma unroll
    for (int i = 0; i < 3; ++i)
      *(ushort4*)&sXh[xrow[i] * 40 + xc4[i] * 4] = xr[i];
    {
      half4v h;
      h[0] = (_Float16)wr.x; h[1] = (_Float16)wr.y;
      h[2] = (_Float16)wr.z; h[3] = (_Float16)wr.w;
      *(half4v*)&sWh[wrow * 40 + wc4 * 4] = h;
    }
    __syncthreads();
    if (c < 124) {
#pragma unroll
      for (int i = 0; i < 3; ++i) xr[i] = px[i][(c + 1) * 8];
      wr = pw[(c + 1) * 8];
    }
    half8 bfrag = *(const half8*)&sWh[(jt * 16 + l15) * 40 + colh];
#pragma unroll
    for (int t = 0; t < 3; ++t) {
      half8 afrag = *(const half8*)&sXh[(mh * 48 + t * 16 + l15) * 40 + colh];
      acc[t] = __builtin_amdgcn_mfma_f32_16x16x32_f16(afrag, bfrag, acc[t], 0, 0, 0);
    }
  }

  // D: col = lane&15 (j), row m = (lane>>4)*4 + reg  [validated rounds 3-4]
  float* out = gip + (size_t)blockIdx.y * (MM * G3);
  int j = jb + jt * 16 + l15;
#pragma unroll
  for (int t = 0; t < 3; ++t) {
    int mb = mh * 48 + t * 16 + (lane >> 4) * 4;
#pragma unroll
    for (int r = 0; r < 4; ++r)
      out[(size_t)(mb + r) * G3 + j] = acc[t][r];
  }
}

// ------------------------------------------------- GRU step 0 (h=0 -> gh=0)
__global__ __launch_bounds__(256) void k_gates0(const float* __restrict__ gip,
                                                const float* __restrict__ b_ih,
                                                const float* __restrict__ b_hh,
                                                float* __restrict__ h32n,
                                                _Float16* __restrict__ h16n) {
  int idx = blockIdx.x * 256 + threadIdx.x;   // 32000 exact (125 blocks)
  int q = idx >> 3, m = idx & 7;
  const float* g0 = gip + (size_t)m * G3;                     // t=0: mg = m
  const float* g1 = gip + (size_t)MM * G3 + (size_t)m * G3;
  float ir  = b_ih[q]          + g0[q]          + g1[q];
  float iz  = b_ih[q + HG]     + g0[q + HG]     + g1[q + HG];
  float in_ = b_ih[q + 2*HG]   + g0[q + 2*HG]   + g1[q + 2*HG];
  float r = 1.f / (1.f + __expf(-(ir + b_hh[q])));
  float z = 1.f / (1.f + __expf(-(iz + b_hh[q + HG])));
  float nn = tanhf(in_ + r * b_hh[q + 2*HG]);
  float h = (1.f - z) * nn;                   // h_old = 0
  h32n[idx] = h;
  h16n[idx] = (_Float16)h;
}

// ------------------------------------------------- fused GRU step (gh + gates)
// block 256 = 16 ks x 16 q;  grid 250 (16 q per block).
// W rows {q, q+HG, q+2HG} fp16 padded to 4096; h staged in LDS fp16 [4096][8].
__device__ __forceinline__ int swzu(int u) { return u ^ ((u >> 3) & 7); }

__global__ __launch_bounds__(256) void k_gru(const _Float16* __restrict__ wh,
                                             const float* __restrict__ gip,
                                             const float* __restrict__ b_ih,
                                             const float* __restrict__ b_hh,
                                             const _Float16* __restrict__ h16,
                                             const float* __restrict__ h32,
                                             float* __restrict__ h32n,
                                             _Float16* __restrict__ h16n,
                                             float* __restrict__ out, int t) {
  __shared__ half8 sH[KP];              // 64 KB, unit u = source index k
  __shared__ float sAcc[16][3][8];
  int tid = threadIdx.x;
  const half8* __restrict__ g8 = (const half8*)h16;
  half8 zz = {};
#pragma unroll
  for (int i = 0; i < 16; ++i) {
    int u = i * 256 + tid;
    sH[swzu(u)] = (u < HG) ? g8[u] : zz;
  }
  __syncthreads();

  int ks = tid & 15, q_l = tid >> 4;
  int q = blockIdx.x * 16 + q_l;
  const half8* __restrict__ W0 = (const half8*)(wh + (size_t)q * KP);
  const half8* __restrict__ W1 = (const half8*)(wh + (size_t)(q + HG) * KP);
  const half8* __restrict__ W2 = (const half8*)(wh + (size_t)(q + 2 * HG) * KP);

  float acc0[8] = {}, acc1[8] = {}, acc2[8] = {};
  // chunk ck = c*16 + ks  (wave-contiguous W loads), software pipeline depth 2
  half8 wa0 = W0[ks],      wa1 = W1[ks],      wa2 = W2[ks];
  half8 wb0 = W0[16 + ks], wb1 = W1[16 + ks], wb2 = W2[16 + ks];
#pragma unroll
  for (int c = 0; c < 32; ++c) {
    half8 w0, w1, w2;
    if ((c & 1) == 0) { w0 = wa0; w1 = wa1; w2 = wa2; }
    else              { w0 = wb0; w1 = wb1; w2 = wb2; }
    if (c + 2 < 32) {
      int ck2 = (c + 2) * 16 + ks;
      if ((c & 1) == 0) { wa0 = W0[ck2]; wa1 = W1[ck2]; wa2 = W2[ck2]; }
      else              { wb0 = W0[ck2]; wb1 = W1[ck2]; wb2 = W2[ck2]; }
    }
    int ck = c * 16 + ks;
#pragma unroll
    for (int kk = 0; kk < 8; ++kk) {
      half8 h8 = sH[swzu(ck * 8 + kk)];
      float f0 = (float)w0[kk], f1 = (float)w1[kk], f2 = (float)w2[kk];
#pragma unroll
      for (int m = 0; m < 8; ++m) {
        float hm = (float)h8[m];
        acc0[m] += hm * f0;
        acc1[m] += hm * f1;
        acc2[m] += hm * f2;
      }
    }
  }
  // reduce over ks (16 lanes per group)
#pragma unroll
  for (int m = 0; m < 8; ++m) {
    float a0 = acc0[m], a1 = acc1[m], a2 = acc2[m];
#pragma unroll
    for (int d = 8; d; d >>= 1) {
      a0 += __shfl_down(a0, d, 16);
      a1 += __shfl_down(a1, d, 16);
      a2 += __shfl_down(a2, d, 16);
    }
    if (ks == 0) {
      sAcc[q_l][0][m] = a0; sAcc[q_l][1][m] = a1; sAcc[q_l][2][m] = a2;
    }
  }
  __syncthreads();

  if (tid < 128) {
    int ql2 = tid >> 3, m = tid & 7;
    int qq = blockIdx.x * 16 + ql2;
    int mg = t * BB + m;
    const float* g0 = gip + (size_t)mg * G3;
    const float* g1 = gip + (size_t)MM * G3 + (size_t)mg * G3;
    float ir  = b_ih[qq]          + g0[qq]          + g1[qq];
    float iz  = b_ih[qq + HG]     + g0[qq + HG]     + g1[qq + HG];
    float in_ = b_ih[qq + 2*HG]   + g0[qq + 2*HG]   + g1[qq + 2*HG];
    float hr  = b_hh[qq]          + sAcc[ql2][0][m];
    float hz  = b_hh[qq + HG]     + sAcc[ql2][1][m];
    float hn  = b_hh[qq + 2*HG]   + sAcc[ql2][2][m];
    float r = 1.f / (1.f + __expf(-(ir + hr)));
    float z = 1.f / (1.f + __expf(-(iz + hz)));
    float nn = tanhf(in_ + r * hn);
    float ho = h32[qq * BB + m];
    float h = (1.f - z) * nn + z * ho;
    h32n[qq * BB + m] = h;
    h16n[qq * BB + m] = (_Float16)h;
    if (out) out[m * HG + qq] = h;
  }
}

// ---------------------------------------------------------------- launcher
extern "C" void kernel_launch(void* const* d_in, const int* in_sizes, int n_in,
                              void* d_out, int out_size, void* d_ws, size_t ws_size,
                              hipStream_t stream) {
  const float* x_in = (const float*)d_in[0];
  const int*   src  = (const int*)d_in[1];
  const int*   dst  = (const int*)d_in[2];
  const float* W1   = (const float*)d_in[3];
  const float* b1   = (const float*)d_in[4];
  const float* W2   = (const float*)d_in[5];
  const float* b2   = (const float*)d_in[6];
  const float* W3   = (const float*)d_in[7];
  const float* b3   = (const float*)d_in[8];
  const float* Wih  = (const float*)d_in[9];
  const float* Whh  = (const float*)d_in[10];
  const float* bih  = (const float*)d_in[11];
  const float* bhh  = (const float*)d_in[12];
  float* out = (float*)d_out;

  float* W = (float*)d_ws;
  size_t off = 0;
  float* n_out = W + off; off += 512;
  float* n_in_ = W + off; off += 512;
  float* x0    = W + off; off += (size_t)TT * NN * BB * FIN;   // 384000
  float* xa    = W + off; off += (size_t)TT * NN * BB * HH;    // 768000
  float* xb    = W + off; off += (size_t)TT * NN * BB * HH;    // 768000
  _Float16* xseq = (_Float16*)(W + off); off += (size_t)MM * IG / 2;
  float* gip   = W + off; off += (size_t)2 * MM * G3;          // 2304000
  float* ht32a = W + off; off += (size_t)HG * BB;
  float* ht32b = W + off; off += (size_t)HG * BB;
  _Float16* ht16a = (_Float16*)(W + off); off += (size_t)HG * BB / 2;
  _Float16* ht16b = (_Float16*)(W + off); off += (size_t)HG * BB / 2;
  int* row_ptr  = (int*)(W + off); off += 512;
  int* edge_src = (int*)(W + off); off += 8000;
  off = (off + 3) & ~(size_t)3;                                // 16B align
  _Float16* whh_h = (_Float16*)(W + off); off += (size_t)G3 * KP / 2;  // 98.3 MB
  (void)ws_size; (void)in_sizes; (void)n_in; (void)out_size;

  k_cvt_whh<<<(G3 * (KP / 8)) / 256, 256, 0, stream>>>(Whh, whh_h);   // 24000 blocks
  k_prep<<<1, 512, 0, stream>>>(src, dst, n_out, n_in_, row_ptr, edge_src);
  k_transpose<<<(TT * NN * BB * FIN + 255) / 256, 256, 0, stream>>>(x_in, x0);
  k_gcn<FIN, HH, true, float, false><<<TT * NN, 128, 0, stream>>>(x0, W1, b1, n_out, n_in_, row_ptr, edge_src, xa);
  k_gcn<HH, HH, true, float, false><<<TT * NN, 128, 0, stream>>>(xa, W2, b2, n_out, n_in_, row_ptr, edge_src, xb);
  k_gcn<HH, HH, false, _Float16, true><<<TT * NN, 128, 0, stream>>>(xb, W3, b3, n_out, n_in_, row_ptr, edge_src, xseq);
  k_gemm_gi_mfma<<<dim3(375, 2), 256, 0, stream>>>(xseq, Wih, gip);

  k_gates0<<<BB * HG / 256, 256, 0, stream>>>(gip, bih, bhh, ht32a, ht16a);

  float* h32c = ht32a; float* h32n = ht32b;
  _Float16* h16c = ht16a; _Float16* h16n = ht16b;
  for (int t = 1; t < TT; ++t) {
    k_gru<<<HG / 16, 256, 0, stream>>>(whh_h, gip, bih, bhh, h16c, h32c,
                                       h32n, h16n, (t == TT - 1) ? out : nullptr, t);
    float* tf = h32c; h32c = h32n; h32n = tf;
    _Float16* th = h16c; h16c = h16n; h16n = th;
  }
}

// Round 6
// 525.872 us; speedup vs baseline: 38.9192x; 38.9192x over previous
//
#include <hip/hip_runtime.h>

#define NN 500
#define BB 8
#define FIN 8
#define TT 12
#define HH 16
#define EE 8000
#define HG 4000          // N*HID
#define IG 8000          // N*H3
#define G3 12000         // 3*HG
#define MM 96            // T*B

typedef __attribute__((ext_vector_type(8))) _Float16 half8;
typedef __attribute__((ext_vector_type(4))) _Float16 half4v;
typedef __attribute__((ext_vector_type(4))) float f32x4;

// ---------------------------------------------------------------- graph prep
__global__ __launch_bounds__(512) void k_prep(const int* __restrict__ src,
                                              const int* __restrict__ dst,
                                              float* __restrict__ n_out,
                                              float* __restrict__ n_in,
                                              int* __restrict__ row_ptr,
                                              int* __restrict__ edge_src) {
  __shared__ int s_dout[NN];
  __shared__ int s_din[NN];
  __shared__ int s_off[NN + 1];
  int tid = threadIdx.x;
  for (int i = tid; i < NN; i += 512) { s_dout[i] = 0; s_din[i] = 0; }
  __syncthreads();
  for (int e = tid; e < EE; e += 512) {
    atomicAdd(&s_dout[src[e]], 1);
    atomicAdd(&s_din[dst[e]], 1);
  }
  __syncthreads();
  if (tid == 0) {
    int acc = 0;
    for (int n = 0; n < NN; ++n) { s_off[n] = acc; acc += s_din[n]; }
    s_off[NN] = acc;
  }
  __syncthreads();
  for (int i = tid; i < NN; i += 512) {
    int dv = s_dout[i]; if (dv < 1) dv = 1;
    int iv = s_din[i];  if (iv < 1) iv = 1;
    n_out[i] = rsqrtf((float)dv);
    n_in[i]  = rsqrtf((float)iv);
    row_ptr[i] = s_off[i];
  }
  if (tid == 0) row_ptr[NN] = s_off[NN];
  __syncthreads();
  for (int e = tid; e < EE; e += 512) {
    int d = dst[e];
    int pos = atomicAdd(&s_off[d], 1);
    edge_src[pos] = src[e];
  }
}

// ------------------------------------------------- transpose inputs to [t][n][b][f]
__global__ __launch_bounds__(256) void k_transpose(const float* __restrict__ in,
                                                   float* __restrict__ out) {
  int idx = blockIdx.x * 256 + threadIdx.x;   // over T*N*B*FIN
  if (idx >= TT * NN * BB * FIN) return;
  int f = idx % FIN;
  int b = (idx / FIN) % BB;
  int n = (idx / (FIN * BB)) % NN;
  int t = idx / (FIN * BB * NN);
  out[idx] = in[((n * BB + b) * FIN + f) * TT + t];
}

// ---------------------------------------------------------------- GCN layer
template <int FI, int FO, bool RELU, typename OT, bool OUT_SEQ>
__global__ __launch_bounds__(128) void k_gcn(const float* __restrict__ x,
                                             const float* __restrict__ W,
                                             const float* __restrict__ bias,
                                             const float* __restrict__ n_out,
                                             const float* __restrict__ n_in,
                                             const int* __restrict__ row_ptr,
                                             const int* __restrict__ edge_src,
                                             OT* __restrict__ y) {
  int bid = blockIdx.x;             // t*NN + n
  int t = bid / NN, n = bid % NN;
  __shared__ float sW[FI * FO];
  __shared__ float sB[FO];
  __shared__ float sAgg[BB * FI];
  int tid = threadIdx.x;
  for (int i = tid; i < FI * FO; i += 128) sW[i] = W[i];
  if (tid < FO) sB[tid] = bias[tid];
  int r0 = row_ptr[n], r1 = row_ptr[n + 1];
  if (tid < BB * FI) {
    int b = tid / FI, fi = tid % FI;
    float acc = 0.f;
    for (int p = r0; p < r1; ++p) {
      int s = edge_src[p];
      acc += x[((t * NN + s) * BB + b) * FI + fi] * n_out[s];
    }
    sAgg[tid] = acc * n_in[n];
  }
  __syncthreads();
  if (tid < BB * FO) {
    int b = tid / FO, fo = tid % FO;
    float v = sB[fo];
#pragma unroll
    for (int fi = 0; fi < FI; ++fi) v += sAgg[b * FI + fi] * sW[fi * FO + fo];
    if (RELU) v = fmaxf(v, 0.f);
    int oidx = OUT_SEQ ? (((t * BB + b) * NN + n) * FO + fo)
                       : (((t * NN + n) * BB + b) * FO + fo);
    y[oidx] = (OT)v;
  }
}

// ------------------------------------------------- Whh fp32 -> fp16 (once)
__global__ __launch_bounds__(256) void k_cvt_whh(const float* __restrict__ w,
                                                 _Float16* __restrict__ wh) {
  size_t i8 = ((size_t)blockIdx.x * 256 + threadIdx.x) * 8;
  if (i8 >= (size_t)G3 * HG) return;
  float4 a = *(const float4*)(w + i8);
  float4 b = *(const float4*)(w + i8 + 4);
  half8 h;
  h[0] = (_Float16)a.x; h[1] = (_Float16)a.y; h[2] = (_Float16)a.z; h[3] = (_Float16)a.w;
  h[4] = (_Float16)b.x; h[5] = (_Float16)b.y; h[6] = (_Float16)b.z; h[7] = (_Float16)b.w;
  *(half8*)(wh + i8) = h;
}

// ------------------------------------------------------------ gi = X @ Wih^T
// fp16 MFMA single pass.  Xh: [96][8000] fp16, Wih: [12000][8000] fp32 (cvt in-kernel).
// gip: [2][96][12000] K-split partials.  grid (375, 2), block 256 (4 waves).
__global__ __launch_bounds__(256, 3) void k_gemm_gi_mfma(const _Float16* __restrict__ Xh,
                                                         const float* __restrict__ Wih,
                                                         float* __restrict__ gip) {
  __shared__ _Float16 sXh[96 * 40];   // rows padded to 40 halves (80B stride)
  __shared__ _Float16 sWh[32 * 40];
  int tid = threadIdx.x;
  int wave = tid >> 6, lane = tid & 63;
  int jb = blockIdx.x * 32;
  int kbase = blockIdx.y * 4000;       // K_s = 4000, 125 chunks of 32

  int xrow[3], xc4[3];
  const ushort4* px[3];
#pragma unroll
  for (int i = 0; i < 3; ++i) {
    int idx = i * 256 + tid;           // 768 units = 96 rows x 8 half4
    xrow[i] = idx >> 3; xc4[i] = idx & 7;
    px[i] = (const ushort4*)(Xh + (size_t)xrow[i] * IG + kbase + xc4[i] * 4);
  }
  int wrow = tid >> 3, wc4 = tid & 7;  // 256 f4 = 32 rows x 8 f4
  const float4* pw = (const float4*)(Wih + (size_t)(jb + wrow) * IG + kbase + wc4 * 4);

  int jt = wave & 1;                    // j-tile within block
  int mh = wave >> 1;                   // m-half (48 rows)
  f32x4 acc[3] = {{0.f,0.f,0.f,0.f},{0.f,0.f,0.f,0.f},{0.f,0.f,0.f,0.f}};

  ushort4 xr[3]; float4 wr;
#pragma unroll
  for (int i = 0; i < 3; ++i) xr[i] = px[i][0];
  wr = pw[0];

  int l15 = lane & 15;
  int colh = (lane >> 4) * 8;

  for (int c = 0; c < 125; ++c) {
    __syncthreads();
#pragma unroll
    for (int i = 0; i < 3; ++i)
      *(ushort4*)&sXh[xrow[i] * 40 + xc4[i] * 4] = xr[i];
    {
      half4v h;
      h[0] = (_Float16)wr.x; h[1] = (_Float16)wr.y;
      h[2] = (_Float16)wr.z; h[3] = (_Float16)wr.w;
      *(half4v*)&sWh[wrow * 40 + wc4 * 4] = h;
    }
    __syncthreads();
    if (c < 124) {
#pragma unroll
      for (int i = 0; i < 3; ++i) xr[i] = px[i][(c + 1) * 8];
      wr = pw[(c + 1) * 8];
    }
    half8 bfrag = *(const half8*)&sWh[(jt * 16 + l15) * 40 + colh];
#pragma unroll
    for (int t = 0; t < 3; ++t) {
      half8 afrag = *(const half8*)&sXh[(mh * 48 + t * 16 + l15) * 40 + colh];
      acc[t] = __builtin_amdgcn_mfma_f32_16x16x32_f16(afrag, bfrag, acc[t], 0, 0, 0);
    }
  }

  // D: col = lane&15 (j), row m = (lane>>4)*4 + reg  [validated rounds 3-5]
  float* out = gip + (size_t)blockIdx.y * (MM * G3);
  int j = jb + jt * 16 + l15;
#pragma unroll
  for (int t = 0; t < 3; ++t) {
    int mb = mh * 48 + t * 16 + (lane >> 4) * 4;
#pragma unroll
    for (int r = 0; r < 4; ++r)
      out[(size_t)(mb + r) * G3 + j] = acc[t][r];
  }
}

// ------------------------------------------------------------ gh = h @ Whh^T
// ht: [4000][8] fp32 k-major, Whh_h: [12000][4000] fp16, ghp: [4][8][12000].
// grid (125, 4), block 256.  96 j per block (3 rows/thread), 1000 k per slice.
__device__ __forceinline__ int swz2(int f) { return f ^ (((f >> 4) & 7) << 1); }

__global__ __launch_bounds__(256) void k_gemm_gh(const float* __restrict__ ht,
                                                 const _Float16* __restrict__ Whh_h,
                                                 float* __restrict__ ghp) {
  int j0 = blockIdx.x * 96;
  int ks = blockIdx.y;             // 0..3
  int kbase = ks * 1000;           // halves
  __shared__ float4 sH4[2000];     // [1000 k][8 m] as float4 pairs, swizzled
  int tid = threadIdx.x;
  const float4* H4 = (const float4*)ht;
#pragma unroll
  for (int l = 0; l < 8; ++l) {
    int f = l * 256 + tid;
    if (f < 2000) sH4[swz2(f)] = H4[kbase * 2 + f];
  }
  __syncthreads();
  int jl = tid >> 3;               // 0..31
  int k8 = tid & 7;                // 0..7
  const half8* W0 = (const half8*)(Whh_h + (size_t)(j0 + jl)      * HG + kbase);
  const half8* W1 = (const half8*)(Whh_h + (size_t)(j0 + jl + 32) * HG + kbase);
  const half8* W2 = (const half8*)(Whh_h + (size_t)(j0 + jl + 64) * HG + kbase);
  float acc[3][8] = {};
  for (int i = 0; i < 16; ++i) {
    int kq = i * 8 + k8;           // half8 index within slice, 0..124
    if (kq < 125) {
      half8 w0 = W0[kq], w1 = W1[kq], w2 = W2[kq];
#pragma unroll
      for (int kk = 0; kk < 8; ++kk) {
        int f = (kq * 8 + kk) * 2;
        float4 ha = sH4[swz2(f)];
        float4 hb = sH4[swz2(f + 1)];
        float hm[8] = {ha.x, ha.y, ha.z, ha.w, hb.x, hb.y, hb.z, hb.w};
        float v0 = (float)w0[kk], v1 = (float)w1[kk], v2 = (float)w2[kk];
#pragma unroll
        for (int m = 0; m < 8; ++m) {
          acc[0][m] += hm[m] * v0;
          acc[1][m] += hm[m] * v1;
          acc[2][m] += hm[m] * v2;
        }
      }
    }
  }
#pragma unroll
  for (int r = 0; r < 3; ++r)
#pragma unroll
    for (int m = 0; m < 8; ++m) {
      float v = acc[r][m];
      v += __shfl_down(v, 4, 8);
      v += __shfl_down(v, 2, 8);
      v += __shfl_down(v, 1, 8);
      acc[r][m] = v;
    }
  if (k8 == 0) {
    float* outp = ghp + (size_t)ks * (BB * G3);
#pragma unroll
    for (int r = 0; r < 3; ++r) {
      int j = j0 + jl + r * 32;
#pragma unroll
      for (int m = 0; m < 8; ++m) outp[m * G3 + j] = acc[r][m];
    }
  }
}

// ------------------------------------------------- GRU step 0 (h=0 -> gh=0)
__global__ __launch_bounds__(256) void k_gates0(const float* __restrict__ gip,
                                                const float* __restrict__ b_ih,
                                                const float* __restrict__ b_hh,
                                                float* __restrict__ h32n) {
  int idx = blockIdx.x * 256 + threadIdx.x;   // 32000 exact (125 blocks)
  int q = idx >> 3, m = idx & 7;
  const float* g0 = gip + (size_t)m * G3;                     // t=0: mg = m
  const float* g1 = gip + (size_t)MM * G3 + (size_t)m * G3;
  float ir  = b_ih[q]          + g0[q]          + g1[q];
  float iz  = b_ih[q + HG]     + g0[q + HG]     + g1[q + HG];
  float in_ = b_ih[q + 2*HG]   + g0[q + 2*HG]   + g1[q + 2*HG];
  float r = 1.f / (1.f + __expf(-(ir + b_hh[q])));
  float z = 1.f / (1.f + __expf(-(iz + b_hh[q + HG])));
  float nn = tanhf(in_ + r * b_hh[q + 2*HG]);
  h32n[idx] = (1.f - z) * nn;                 // h_old = 0
}

// ---------------------------------------------------------------- gates
__global__ __launch_bounds__(256) void k_gates(const float* __restrict__ gip,
                                               const float* __restrict__ ghp,
                                               const float* __restrict__ b_ih,
                                               const float* __restrict__ b_hh,
                                               const float* __restrict__ ht_old,
                                               float* __restrict__ ht_new,
                                               float* __restrict__ hout, int t) {
  int idx = blockIdx.x * 256 + threadIdx.x;
  if (idx >= BB * HG) return;
  int b = idx / HG, q = idx % HG;
  int m = t * BB + b;
  const float* g0 = gip;
  const float* g1 = gip + (size_t)MM * G3;
  float ir = b_ih[q]          + g0[m * G3 + q]          + g1[m * G3 + q];
  float iz = b_ih[q + HG]     + g0[m * G3 + q + HG]     + g1[m * G3 + q + HG];
  float in_ = b_ih[q + 2*HG]  + g0[m * G3 + q + 2*HG]   + g1[m * G3 + q + 2*HG];
  float hr = b_hh[q], hz = b_hh[q + HG], hn = b_hh[q + 2*HG];
#pragma unroll
  for (int s = 0; s < 4; ++s) {
    const float* gh = ghp + (size_t)s * (BB * G3) + b * G3;
    hr += gh[q]; hz += gh[q + HG]; hn += gh[q + 2*HG];
  }
  float r = 1.f / (1.f + __expf(-(ir + hr)));
  float z = 1.f / (1.f + __expf(-(iz + hz)));
  float nn = tanhf(in_ + r * hn);
  float ho = ht_old[q * BB + b];
  float h = (1.f - z) * nn + z * ho;
  ht_new[q * BB + b] = h;
  if (hout) hout[b * HG + q] = h;
}

// ---------------------------------------------------------------- launcher
extern "C" void kernel_launch(void* const* d_in, const int* in_sizes, int n_in,
                              void* d_out, int out_size, void* d_ws, size_t ws_size,
                              hipStream_t stream) {
  const float* x_in = (const float*)d_in[0];
  const int*   src  = (const int*)d_in[1];
  const int*   dst  = (const int*)d_in[2];
  const float* W1   = (const float*)d_in[3];
  const float* b1   = (const float*)d_in[4];
  const float* W2   = (const float*)d_in[5];
  const float* b2   = (const float*)d_in[6];
  const float* W3   = (const float*)d_in[7];
  const float* b3   = (const float*)d_in[8];
  const float* Wih  = (const float*)d_in[9];
  const float* Whh  = (const float*)d_in[10];
  const float* bih  = (const float*)d_in[11];
  const float* bhh  = (const float*)d_in[12];
  float* out = (float*)d_out;

  float* W = (float*)d_ws;
  size_t off = 0;
  float* n_out = W + off; off += 512;
  float* n_in_ = W + off; off += 512;
  float* x0    = W + off; off += (size_t)TT * NN * BB * FIN;   // 384000
  float* xa    = W + off; off += (size_t)TT * NN * BB * HH;    // 768000
  float* xb    = W + off; off += (size_t)TT * NN * BB * HH;    // 768000
  _Float16* xseq = (_Float16*)(W + off); off += (size_t)MM * IG / 2;
  float* gip   = W + off; off += (size_t)2 * MM * G3;          // 2304000
  float* ghp   = W + off; off += (size_t)4 * BB * G3;          // 384000
  float* ht0   = W + off; off += (size_t)HG * BB;
  float* ht1   = W + off; off += (size_t)HG * BB;
  int* row_ptr  = (int*)(W + off); off += 512;
  int* edge_src = (int*)(W + off); off += 8000;
  off = (off + 3) & ~(size_t)3;                                // 16B align
  _Float16* whh_h = (_Float16*)(W + off); off += (size_t)G3 * HG / 2;  // 96 MB
  (void)ws_size; (void)in_sizes; (void)n_in; (void)out_size;

  k_cvt_whh<<<((size_t)G3 * HG / 8 + 255) / 256, 256, 0, stream>>>(Whh, whh_h);
  k_prep<<<1, 512, 0, stream>>>(src, dst, n_out, n_in_, row_ptr, edge_src);
  k_transpose<<<(TT * NN * BB * FIN + 255) / 256, 256, 0, stream>>>(x_in, x0);
  k_gcn<FIN, HH, true, float, false><<<TT * NN, 128, 0, stream>>>(x0, W1, b1, n_out, n_in_, row_ptr, edge_src, xa);
  k_gcn<HH, HH, true, float, false><<<TT * NN, 128, 0, stream>>>(xa, W2, b2, n_out, n_in_, row_ptr, edge_src, xb);
  k_gcn<HH, HH, false, _Float16, true><<<TT * NN, 128, 0, stream>>>(xb, W3, b3, n_out, n_in_, row_ptr, edge_src, xseq);
  k_gemm_gi_mfma<<<dim3(375, 2), 256, 0, stream>>>(xseq, Wih, gip);

  // t = 0: h_old = 0 -> gh = 0, skip the W_hh stream entirely
  k_gates0<<<BB * HG / 256, 256, 0, stream>>>(gip, bih, bhh, ht0);

  float* hcur = ht0;
  float* hnxt = ht1;
  for (int t = 1; t < TT; ++t) {
    k_gemm_gh<<<dim3(125, 4), 256, 0, stream>>>(hcur, whh_h, ghp);
    k_gates<<<(BB * HG + 255) / 256, 256, 0, stream>>>(
        gip, ghp, bih, bhh, hcur, hnxt, (t == TT - 1) ? out : nullptr, t);
    float* tmp = hcur; hcur = hnxt; hnxt = tmp;
  }
}